// Round 5
// baseline (611.505 us; speedup 1.0000x reference)
//
#include <hip/hip_runtime.h>
#include <stdint.h>

// PositionLinearAttention on MI355X. B=8, C=256, Cqk=32, N=16384.
// R9: pass1 = R4's proven per-thread structure (194us datum) at 2x waves:
// 512-thread blocks, grid 512 -> 16 waves/CU (R4 was 8, grid-limited).
//   phase A: thread=(pixel, K/Q-half): each computes its full 32-dim K or Q
//            vector -> norm is thread-local. Coalesced x loads (lane=pixel);
//            both halves read same addresses in lockstep -> L1 broadcast.
//   phase B: thread=(channel, k-half); halves merged via LDS (kn_s reused,
//            transposed xch[m*256+c] -> conflict-free). Partials: 64/batch,
//            workspace layout identical to the proven 34.5 MB R0 config.
// pass2: 1 px/thread (q[32], ~90 VGPR -> 16-wave bucket; the 2-px variant
//        needed ~130 VGPR -> 8 waves), ci-step 8 for MLP, grid 2048.
// No min-waves launch bounds anywhere (R6 spill lesson).
//
// Reformulation (V never materialized):
//   S[b][m][c']   = sum_n Kn[b][m][n] * x[b][c'][n]
//   matrix[b][m][c] = sum_c' Wv[c][c'] S[b][m][c'] + bv[c]*ksraw[b][m]
//   value_sum[b][c] = sum_c' Wv[c][c'] x_sum[b][c'] + N*bv[c]
//   tailor[n] = 1/(N + Qn[n]·(ksraw+EPS))
//   out[b][c][n] = x + gamma*tailor[n]*(value_sum[c] + Qn[n]·matrix[:,c])

#define NB 8
#define NC 256
#define CQK 32
#define NPIX 16384
#define TN 256                       // pixels per pass1 tile
#define PB1 64                       // pass1 blocks per batch
#define PARTF (CQK*NC + NC + CQK)    // 8480 floats per partial block
#define EPSV 1e-6f

typedef unsigned short bfraw;

__device__ __forceinline__ float bf2f(bfraw u) {
    union { uint32_t i; float f; } v; v.i = ((uint32_t)u) << 16; return v.f;
}
__device__ __forceinline__ void unpack8(uint4 raw, float* xv) {
    xv[0] = bf2f((bfraw)(raw.x & 0xffffu)); xv[1] = bf2f((bfraw)(raw.x >> 16));
    xv[2] = bf2f((bfraw)(raw.y & 0xffffu)); xv[3] = bf2f((bfraw)(raw.y >> 16));
    xv[4] = bf2f((bfraw)(raw.z & 0xffffu)); xv[5] = bf2f((bfraw)(raw.z >> 16));
    xv[6] = bf2f((bfraw)(raw.w & 0xffffu)); xv[7] = bf2f((bfraw)(raw.w >> 16));
}
// DT=0: bf16 input, DT=1: fp32 input
template<int DT> __device__ __forceinline__ float ldx(const void* p, size_t i) {
    if (DT) return ((const float*)p)[i];
    return bf2f(((const bfraw*)p)[i]);
}
template<int DT> __device__ __forceinline__ void ld8(const void* p, size_t i, float* o) {
    if (DT) {
        const float4* q = (const float4*)((const float*)p + i);
        float4 a = q[0], b = q[1];
        o[0]=a.x;o[1]=a.y;o[2]=a.z;o[3]=a.w;o[4]=b.x;o[5]=b.y;o[6]=b.z;o[7]=b.w;
    } else {
        uint4 raw = *(const uint4*)((const bfraw*)p + i);
        unpack8(raw, o);
    }
}

// ---- detect dtype + prep weights (merged, 1 block) ----------------------------
// Fused weight layout wkqT[c][0..31]=Wk col c, [32..63]=Wq col c. bkq likewise.
template<int DT> __device__ __forceinline__ void prep_body(
    const void* Wq, const void* bq, const void* Wk, const void* bk,
    float* wkqT, float* bkq) {
    int tid = threadIdx.x;
    for (int i = tid; i < CQK*NC; i += 256) {
        int m = i >> 8, c = i & 255;
        wkqT[c*64 + m]      = ldx<DT>(Wk, i);
        wkqT[c*64 + 32 + m] = ldx<DT>(Wq, i);
    }
    if (tid < CQK)      bkq[tid]      = ldx<DT>(bk, tid);
    else if (tid < 64)  bkq[tid]      = ldx<DT>(bq, tid - 32);
}
__global__ __launch_bounds__(256) void detprep_kernel(
    const bfraw* __restrict__ xr, const void* Wq, const void* bq,
    const void* Wk, const void* bk,
    int* __restrict__ flag, float* __restrict__ wkqT, float* __restrict__ bkq) {
    __shared__ int cnt, ez, fl_s;
    int tid = threadIdx.x;
    if (tid == 0) { cnt = 0; ez = 0; }
    __syncthreads();
    int crazy = 0, evenzero = 0;
    for (int i = tid; i < 2048; i += 256) {
        bfraw u = xr[i];
        float v = bf2f(u);
        float a = fabsf(v);
        if (!(a <= 1e10f) || (v != 0.f && a < 1e-10f)) crazy++;
        if ((i & 1) == 0 && u == 0) evenzero++;
    }
    atomicAdd(&cnt, crazy);
    atomicAdd(&ez, evenzero);
    __syncthreads();
    if (tid == 0) { fl_s = (cnt > 64 || ez > 900) ? 1 : 0; flag[0] = fl_s; }
    __syncthreads();
    if (fl_s) prep_body<1>(Wq, bq, Wk, bk, wkqT, bkq);
    else      prep_body<0>(Wq, bq, Wk, bk, wkqT, bkq);
}

// ---- pass 1: K+Q proj (thread-local norm); Qn -> global; partial S ------------
// Grid NB*PB1 blocks, 512 threads.
//   phase A: thread t = (px = t&255, half = t>>8). half 0 -> K[0..31],
//            half 1 -> Q[0..31]. Full 256-channel dot per thread.
//   phase B: thread t = (c = t&255, h = t>>8). h sums k in [h*128, h*128+128).
template<int DT> __device__ __forceinline__ void pass1_body(
    const void* __restrict__ x, const float* __restrict__ wkqT,
    const float* __restrict__ bkq, float4* __restrict__ qn4,
    float* __restrict__ partial,
    float (*kn_s)[36], float* __restrict__ ks2, float* __restrict__ xsx) {
    const int tid  = threadIdx.x;            // 0..511
    const int b    = blockIdx.x >> 6;        // / PB1
    const int j    = blockIdx.x & (PB1 - 1);
    const int n0   = j * TN;
    const int px   = tid & 255;
    const int half = tid >> 8;               // wave-uniform (waves 0-3 / 4-7)
    const size_t xb = (size_t)b * NC * NPIX;

    // ---- phase A: 32 outputs (K or Q) for pixel px over 256 channels ----
    float kq[32];
    #pragma unroll
    for (int i = 0; i < 32; ++i) kq[i] = bkq[half*32 + i];
    {
        const size_t pixi = xb + (size_t)n0 + px;
        for (int c = 0; c < NC; c += 2) {
            float x0 = ldx<DT>(x, pixi + (size_t)c * NPIX);
            float x1 = ldx<DT>(x, pixi + (size_t)(c+1) * NPIX);
            const float4* w0 = (const float4*)(wkqT + c*64 + half*32);     // uniform
            const float4* w1 = (const float4*)(wkqT + (c+1)*64 + half*32); // uniform
            #pragma unroll
            for (int m4 = 0; m4 < 8; ++m4) {
                float4 a = w0[m4], bb = w1[m4];
                kq[m4*4+0] += a.x*x0; kq[m4*4+0] += bb.x*x1;
                kq[m4*4+1] += a.y*x0; kq[m4*4+1] += bb.y*x1;
                kq[m4*4+2] += a.z*x0; kq[m4*4+2] += bb.z*x1;
                kq[m4*4+3] += a.w*x0; kq[m4*4+3] += bb.w*x1;
            }
        }
    }
    float ss = 0.f;
    #pragma unroll
    for (int i = 0; i < 32; ++i) ss += kq[i]*kq[i];
    float inv = rsqrtf(ss);

    if (half == 0) {
        float4* r = (float4*)&kn_s[px][0];
        #pragma unroll
        for (int m4 = 0; m4 < 8; ++m4)
            r[m4] = make_float4(kq[m4*4+0]*inv, kq[m4*4+1]*inv,
                                kq[m4*4+2]*inv, kq[m4*4+3]*inv);
    } else {
        float4* qp = qn4 + (size_t)b * 8 * NPIX + (n0 + px);
        #pragma unroll
        for (int m4 = 0; m4 < 8; ++m4)
            qp[(size_t)m4 * NPIX] =
                make_float4(kq[m4*4+0]*inv, kq[m4*4+1]*inv,
                            kq[m4*4+2]*inv, kq[m4*4+3]*inv);
    }
    __syncthreads();   // kn_s ready

    // ---- phase B: S[m][c] += sum_{k in half} kn[k][m] * x[c][n0+k] ----
    float sacc[CQK];
    #pragma unroll
    for (int m = 0; m < CQK; ++m) sacc[m] = 0.f;
    float xsacc = 0.f;
    {
        const int c = px, h = half;
        const size_t rowb = xb + (size_t)c * NPIX + n0 + h * 128;
        for (int k0 = 0; k0 < 128; k0 += 8) {
            float xv[8]; ld8<DT>(x, rowb + k0, xv);
            #pragma unroll
            for (int kk = 0; kk < 8; ++kk) {
                const float4* kr = (const float4*)&kn_s[h*128 + k0 + kk][0]; // broadcast
                float xk = xv[kk];
                #pragma unroll
                for (int m4 = 0; m4 < 8; ++m4) {
                    float4 a = kr[m4];
                    sacc[m4*4+0] += a.x*xk; sacc[m4*4+1] += a.y*xk;
                    sacc[m4*4+2] += a.z*xk; sacc[m4*4+3] += a.w*xk;
                }
                xsacc += xk;
            }
        }
    }

    // ---- ksum partials (kn_s still intact): thread (m_, grp) sums 16 rows ----
    {
        const int m_ = tid & 31, grp = tid >> 5;   // grp 0..15
        float kp = 0.f;
        #pragma unroll
        for (int r = 0; r < 16; ++r) kp += kn_s[grp*16 + r][m_];
        ks2[grp*32 + m_] = kp;
    }
    __syncthreads();   // all kn_s reads done -> safe to reuse as xch

    // ---- merge k-halves via LDS; write partials ----
    float* xch = (float*)kn_s;   // 8192 of 9216 floats used, [m][c] layout
    if (half == 1) {
        #pragma unroll
        for (int m = 0; m < CQK; ++m) xch[m*NC + px] = sacc[m];   // conflict-free
        xsx[px] = xsacc;
    }
    __syncthreads();
    const size_t base = (size_t)blockIdx.x * PARTF;
    if (half == 0) {
        #pragma unroll
        for (int m = 0; m < CQK; ++m) sacc[m] += xch[m*NC + px];
        xsacc += xsx[px];
        #pragma unroll
        for (int m = 0; m < CQK; ++m) partial[base + m*NC + px] = sacc[m];
        partial[base + CQK*NC + px] = xsacc;
    }
    if (tid < CQK) {
        float ks = 0.f;
        #pragma unroll
        for (int g = 0; g < 16; ++g) ks += ks2[g*32 + tid];
        partial[base + CQK*NC + NC + tid] = ks;
    }
}
__global__ __launch_bounds__(512) void pass1_kernel(
    const void* __restrict__ x, const float* __restrict__ wkqT,
    const float* __restrict__ bkq, float4* __restrict__ qn4,
    float* __restrict__ partial, const int* __restrict__ flag) {
    __shared__ __align__(16) float kn_s[TN][36];   // 36,864 B (reused as xch)
    __shared__ float ks2[16*32];                   //  2,048 B
    __shared__ float xsx[NC];                      //  1,024 B
    if (flag[0]) pass1_body<1>(x, wkqT, bkq, qn4, partial, kn_s, ks2, xsx);
    else         pass1_body<0>(x, wkqT, bkq, qn4, partial, kn_s, ks2, xsx);
}

// ---- pass 1.5: reduce partials; matrix^T [b][c][32], value_sum, k_sum ---------
template<int DT> __device__ __forceinline__ float dot256(const void* Wv, int row,
                                                         const float* sh) {
    float r = 0.f;
    for (int c0 = 0; c0 < NC; c0 += 8) {
        float xv[8]; ld8<DT>(Wv, (size_t)row * NC + c0, xv);
        #pragma unroll
        for (int i = 0; i < 8; ++i) r += xv[i] * sh[c0+i];
    }
    return r;
}
template<int DT> __device__ __forceinline__ void pass15_body(
    const float* __restrict__ partial, const void* __restrict__ Wv,
    const void* __restrict__ bv, float* __restrict__ matT,
    float* __restrict__ vsum, float* __restrict__ ksum, float* sh) {
    int tid = threadIdx.x;
    int b = blockIdx.x / 33, m = blockIdx.x % 33;
    const float* pb_ = partial + (size_t)b * PB1 * PARTF;

    if (m < CQK) {
        float acc = 0.f;
        #pragma unroll 4
        for (int p = 0; p < PB1; ++p) acc += pb_[(size_t)p*PARTF + m*NC + tid];
        sh[tid] = acc;
        float ks = 0.f;
        #pragma unroll 4
        for (int p = 0; p < PB1; ++p) ks += pb_[(size_t)p*PARTF + CQK*NC + NC + m];
        __syncthreads();
        float r = dot256<DT>(Wv, tid, sh);
        matT[((size_t)b*NC + tid)*CQK + m] = r + ldx<DT>(bv, tid) * ks;
        if (tid == 0) ksum[b*CQK + m] = ks + EPSV;
    } else {
        float acc = 0.f;
        #pragma unroll 4
        for (int p = 0; p < PB1; ++p) acc += pb_[(size_t)p*PARTF + CQK*NC + tid];
        sh[tid] = acc;
        __syncthreads();
        float r = dot256<DT>(Wv, tid, sh);
        vsum[b*NC + tid] = r + (float)NPIX * ldx<DT>(bv, tid);
    }
}
__global__ __launch_bounds__(256) void pass15_kernel(
    const float* __restrict__ partial, const void* __restrict__ Wv,
    const void* __restrict__ bv, float* __restrict__ matT,
    float* __restrict__ vsum, float* __restrict__ ksum,
    const int* __restrict__ flag) {
    __shared__ float sh[NC];
    if (flag[0]) pass15_body<1>(partial, Wv, bv, matT, vsum, ksum, sh);
    else         pass15_body<0>(partial, Wv, bv, matT, vsum, ksum, sh);
}

// ---- pass 2: epilogue. 1 px/thread (low VGPR), ci-step 8 for MLP. -------------
// grid = NB * 64 * 4 : (b, 256-pixel tile, 64-channel chunk)
template<int DT> __device__ __forceinline__ void pass2_body(
    const void* __restrict__ x, const float4* __restrict__ qn4,
    const float* __restrict__ ksum, const float* __restrict__ matT,
    const float* __restrict__ vsum, const void* __restrict__ gamma,
    float* __restrict__ out) {
    int tid = threadIdx.x;
    int bx = blockIdx.x;
    int cs = bx & 3, tile = (bx >> 2) & 63, b = bx >> 8;
    int p = tile * TN + tid;

    float q[CQK];
    const float4* qp = qn4 + (size_t)b * 8 * NPIX + p;
    #pragma unroll
    for (int m4 = 0; m4 < 8; ++m4) {
        float4 a = qp[(size_t)m4 * NPIX];
        q[m4*4+0]=a.x; q[m4*4+1]=a.y; q[m4*4+2]=a.z; q[m4*4+3]=a.w;
    }
    const float* ksb = ksum + b*CQK;   // uniform
    float dot = 0.f;
    #pragma unroll
    for (int m = 0; m < CQK; ++m) dot += q[m] * ksb[m];
    float gt = ldx<DT>(gamma, 0) / ((float)NPIX + dot);

    int c0 = cs * 64;
    const float* mb = matT + ((size_t)b*NC + c0)*CQK;  // uniform rows
    const float* vb = vsum + (size_t)b*NC + c0;
    size_t xbase = (size_t)b*NC*NPIX + (size_t)c0*NPIX + p;

    for (int ci = 0; ci < 64; ci += 8) {
        float xv[8];
        #pragma unroll
        for (int u = 0; u < 8; ++u)
            xv[u] = ldx<DT>(x, xbase + (size_t)(ci+u)*NPIX);
        #pragma unroll
        for (int u = 0; u < 8; ++u) {
            float r = vb[ci+u];
            const float4* mr = (const float4*)(mb + (ci+u)*CQK);  // uniform
            #pragma unroll
            for (int m4 = 0; m4 < 8; ++m4) {
                float4 a = mr[m4];
                r += q[m4*4+0]*a.x + q[m4*4+1]*a.y + q[m4*4+2]*a.z + q[m4*4+3]*a.w;
            }
            out[xbase + (size_t)(ci+u)*NPIX] = xv[u] + gt*r;
        }
    }
}
__global__ __launch_bounds__(256) void pass2_kernel(
    const void* __restrict__ x, const float4* __restrict__ qn4,
    const float* __restrict__ ksum, const float* __restrict__ matT,
    const float* __restrict__ vsum, const void* __restrict__ gamma,
    float* __restrict__ out, const int* __restrict__ flag) {
    if (flag[0]) pass2_body<1>(x, qn4, ksum, matT, vsum, gamma, out);
    else         pass2_body<0>(x, qn4, ksum, matT, vsum, gamma, out);
}

// ---- host ----------------------------------------------------------------------
extern "C" void kernel_launch(void* const* d_in, const int* in_sizes, int n_in,
                              void* d_out, int out_size, void* d_ws, size_t ws_size,
                              hipStream_t stream)
{
    const void* x  = d_in[0];
    const void* Wq = d_in[1];
    const void* bq = d_in[2];
    const void* Wk = d_in[3];
    const void* bk = d_in[4];
    const void* Wv = d_in[5];
    const void* bv = d_in[6];
    const void* gm = d_in[7];
    float* out = (float*)d_out;

    float* ws = (float*)d_ws;
    int*   flag = (int*)ws;             // 16 floats reserved
    float* wkqT = ws + 16;              // 16384
    float* bkq  = wkqT + 64*NC;         // 64
    float* matT = bkq + 64;             // NB*NC*CQK = 65536
    float* vsum = matT + NB*NC*CQK;     // 2048
    float* ksum = vsum + NB*NC;         // 256
    float* qn4f = ksum + NB*CQK;        // NB*8*NPIX*4 = 4194304 (16B-aligned)
    float* partial_ws = qn4f + (size_t)NB*8*NPIX*4;

    // Partial S scratch: NB*PB1*PARTF floats = 17.4 MB; total ws use 34.5 MB ==
    // the R0-proven-fit layout. d_out fallback kept only as a guard.
    size_t fixedf = (size_t)(partial_ws - ws);
    size_t needb  = (fixedf + (size_t)NB*PB1*PARTF) * sizeof(float);
    float* partial = (needb <= ws_size) ? partial_ws : (float*)d_out;

    hipLaunchKernelGGL(detprep_kernel, dim3(1), dim3(256), 0, stream,
                       (const bfraw*)x, Wq, bq, Wk, bk, flag, wkqT, bkq);
    hipLaunchKernelGGL(pass1_kernel, dim3(NB*PB1), dim3(512), 0, stream,
                       x, wkqT, bkq, (float4*)qn4f, partial, flag);
    hipLaunchKernelGGL(pass15_kernel, dim3(NB*33), dim3(256), 0, stream,
                       partial, Wv, bv, matT, vsum, ksum, flag);
    hipLaunchKernelGGL(pass2_kernel, dim3(NB*64*4), dim3(256), 0, stream,
                       x, (const float4*)qn4f, ksum, matT, vsum, gm, out, flag);
}

// Round 6
// 582.977 us; speedup vs baseline: 1.0489x; 1.0489x over previous
//
#include <hip/hip_runtime.h>
#include <stdint.h>

// PositionLinearAttention on MI355X. B=8, C=256, Cqk=32, N=16384.
// R10 = R9 structure (512-thr K/Q-split pass1, 16 waves/CU, thread-local norm)
// + restored R4-style load batching (the MLP that R9's c+=2 loop destroyed:
// VGPR 56, 2 loads in flight, 0.59 TB/s). BW = waves x loads-in-flight:
//   phase A: xv[8] batch -> 8 independent scalar loads per 256 FMAs
//   phase B: k-unroll 16 -> 4 independent float4 loads per 512 FMAs
//   pass2:   ci-step 16  -> 16 independent scalar loads per thread
//
// Reformulation (V never materialized):
//   S[b][m][c']   = sum_n Kn[b][m][n] * x[b][c'][n]
//   matrix[b][m][c] = sum_c' Wv[c][c'] S[b][m][c'] + bv[c]*ksraw[b][m]
//   value_sum[b][c] = sum_c' Wv[c][c'] x_sum[b][c'] + N*bv[c]
//   tailor[n] = 1/(N + Qn[n]·(ksraw+EPS))
//   out[b][c][n] = x + gamma*tailor[n]*(value_sum[c] + Qn[n]·matrix[:,c])

#define NB 8
#define NC 256
#define CQK 32
#define NPIX 16384
#define TN 256                       // pixels per pass1 tile
#define PB1 64                       // pass1 blocks per batch
#define PARTF (CQK*NC + NC + CQK)    // 8480 floats per partial block
#define EPSV 1e-6f

typedef unsigned short bfraw;

__device__ __forceinline__ float bf2f(bfraw u) {
    union { uint32_t i; float f; } v; v.i = ((uint32_t)u) << 16; return v.f;
}
__device__ __forceinline__ void unpack8(uint4 raw, float* xv) {
    xv[0] = bf2f((bfraw)(raw.x & 0xffffu)); xv[1] = bf2f((bfraw)(raw.x >> 16));
    xv[2] = bf2f((bfraw)(raw.y & 0xffffu)); xv[3] = bf2f((bfraw)(raw.y >> 16));
    xv[4] = bf2f((bfraw)(raw.z & 0xffffu)); xv[5] = bf2f((bfraw)(raw.z >> 16));
    xv[6] = bf2f((bfraw)(raw.w & 0xffffu)); xv[7] = bf2f((bfraw)(raw.w >> 16));
}
// DT=0: bf16 input, DT=1: fp32 input
template<int DT> __device__ __forceinline__ float ldx(const void* p, size_t i) {
    if (DT) return ((const float*)p)[i];
    return bf2f(((const bfraw*)p)[i]);
}
template<int DT> __device__ __forceinline__ void ld8(const void* p, size_t i, float* o) {
    if (DT) {
        const float4* q = (const float4*)((const float*)p + i);
        float4 a = q[0], b = q[1];
        o[0]=a.x;o[1]=a.y;o[2]=a.z;o[3]=a.w;o[4]=b.x;o[5]=b.y;o[6]=b.z;o[7]=b.w;
    } else {
        uint4 raw = *(const uint4*)((const bfraw*)p + i);
        unpack8(raw, o);
    }
}

// ---- detect dtype + prep weights (merged, 1 block) ----------------------------
// Fused weight layout wkqT[c][0..31]=Wk col c, [32..63]=Wq col c. bkq likewise.
template<int DT> __device__ __forceinline__ void prep_body(
    const void* Wq, const void* bq, const void* Wk, const void* bk,
    float* wkqT, float* bkq) {
    int tid = threadIdx.x;
    for (int i = tid; i < CQK*NC; i += 256) {
        int m = i >> 8, c = i & 255;
        wkqT[c*64 + m]      = ldx<DT>(Wk, i);
        wkqT[c*64 + 32 + m] = ldx<DT>(Wq, i);
    }
    if (tid < CQK)      bkq[tid]      = ldx<DT>(bk, tid);
    else if (tid < 64)  bkq[tid]      = ldx<DT>(bq, tid - 32);
}
__global__ __launch_bounds__(256) void detprep_kernel(
    const bfraw* __restrict__ xr, const void* Wq, const void* bq,
    const void* Wk, const void* bk,
    int* __restrict__ flag, float* __restrict__ wkqT, float* __restrict__ bkq) {
    __shared__ int cnt, ez, fl_s;
    int tid = threadIdx.x;
    if (tid == 0) { cnt = 0; ez = 0; }
    __syncthreads();
    int crazy = 0, evenzero = 0;
    for (int i = tid; i < 2048; i += 256) {
        bfraw u = xr[i];
        float v = bf2f(u);
        float a = fabsf(v);
        if (!(a <= 1e10f) || (v != 0.f && a < 1e-10f)) crazy++;
        if ((i & 1) == 0 && u == 0) evenzero++;
    }
    atomicAdd(&cnt, crazy);
    atomicAdd(&ez, evenzero);
    __syncthreads();
    if (tid == 0) { fl_s = (cnt > 64 || ez > 900) ? 1 : 0; flag[0] = fl_s; }
    __syncthreads();
    if (fl_s) prep_body<1>(Wq, bq, Wk, bk, wkqT, bkq);
    else      prep_body<0>(Wq, bq, Wk, bk, wkqT, bkq);
}

// ---- pass 1: K+Q proj (thread-local norm); Qn -> global; partial S ------------
// Grid NB*PB1 blocks, 512 threads.
//   phase A: thread t = (px = t&255, half = t>>8). half 0 -> K[0..31],
//            half 1 -> Q[0..31]. Full 256-channel dot per thread.
//   phase B: thread t = (c = t&255, h = t>>8). h sums k in [h*128, h*128+128).
template<int DT> __device__ __forceinline__ void pass1_body(
    const void* __restrict__ x, const float* __restrict__ wkqT,
    const float* __restrict__ bkq, float4* __restrict__ qn4,
    float* __restrict__ partial,
    float (*kn_s)[36], float* __restrict__ ks2, float* __restrict__ xsx) {
    const int tid  = threadIdx.x;            // 0..511
    const int b    = blockIdx.x >> 6;        // / PB1
    const int j    = blockIdx.x & (PB1 - 1);
    const int n0   = j * TN;
    const int px   = tid & 255;
    const int half = tid >> 8;               // wave-uniform (waves 0-3 / 4-7)
    const size_t xb = (size_t)b * NC * NPIX;

    // ---- phase A: 32 outputs (K or Q) for pixel px over 256 channels ----
    float kq[32];
    #pragma unroll
    for (int i = 0; i < 32; ++i) kq[i] = bkq[half*32 + i];
    {
        const size_t pixi = xb + (size_t)n0 + px;
        for (int c0 = 0; c0 < NC; c0 += 8) {
            float xv[8];
            #pragma unroll
            for (int jj = 0; jj < 8; ++jj)
                xv[jj] = ldx<DT>(x, pixi + (size_t)(c0 + jj) * NPIX);
            #pragma unroll
            for (int jj = 0; jj < 8; ++jj) {
                const float4* w = (const float4*)(wkqT + (c0+jj)*64 + half*32); // uniform
                float xk = xv[jj];
                #pragma unroll
                for (int m4 = 0; m4 < 8; ++m4) {
                    float4 a = w[m4];
                    kq[m4*4+0] += a.x*xk; kq[m4*4+1] += a.y*xk;
                    kq[m4*4+2] += a.z*xk; kq[m4*4+3] += a.w*xk;
                }
            }
        }
    }
    float ss = 0.f;
    #pragma unroll
    for (int i = 0; i < 32; ++i) ss += kq[i]*kq[i];
    float inv = rsqrtf(ss);

    if (half == 0) {
        float4* r = (float4*)&kn_s[px][0];
        #pragma unroll
        for (int m4 = 0; m4 < 8; ++m4)
            r[m4] = make_float4(kq[m4*4+0]*inv, kq[m4*4+1]*inv,
                                kq[m4*4+2]*inv, kq[m4*4+3]*inv);
    } else {
        float4* qp = qn4 + (size_t)b * 8 * NPIX + (n0 + px);
        #pragma unroll
        for (int m4 = 0; m4 < 8; ++m4)
            qp[(size_t)m4 * NPIX] =
                make_float4(kq[m4*4+0]*inv, kq[m4*4+1]*inv,
                            kq[m4*4+2]*inv, kq[m4*4+3]*inv);
    }
    __syncthreads();   // kn_s ready

    // ---- phase B: S[m][c] += sum_{k in half} kn[k][m] * x[c][n0+k] ----
    float sacc[CQK];
    #pragma unroll
    for (int m = 0; m < CQK; ++m) sacc[m] = 0.f;
    float xsacc = 0.f;
    {
        const int c = px, h = half;
        const size_t rowb = xb + (size_t)c * NPIX + n0 + h * 128;
        for (int k0 = 0; k0 < 128; k0 += 16) {
            float xv[16];
            ld8<DT>(x, rowb + k0, xv);
            ld8<DT>(x, rowb + k0 + 8, xv + 8);
            #pragma unroll
            for (int kk = 0; kk < 16; ++kk) {
                const float4* kr = (const float4*)&kn_s[h*128 + k0 + kk][0]; // broadcast
                float xk = xv[kk];
                #pragma unroll
                for (int m4 = 0; m4 < 8; ++m4) {
                    float4 a = kr[m4];
                    sacc[m4*4+0] += a.x*xk; sacc[m4*4+1] += a.y*xk;
                    sacc[m4*4+2] += a.z*xk; sacc[m4*4+3] += a.w*xk;
                }
                xsacc += xk;
            }
        }
    }

    // ---- ksum partials (kn_s still intact): thread (m_, grp) sums 16 rows ----
    {
        const int m_ = tid & 31, grp = tid >> 5;   // grp 0..15
        float kp = 0.f;
        #pragma unroll
        for (int r = 0; r < 16; ++r) kp += kn_s[grp*16 + r][m_];
        ks2[grp*32 + m_] = kp;
    }
    __syncthreads();   // all kn_s reads done -> safe to reuse as xch

    // ---- merge k-halves via LDS; write partials ----
    float* xch = (float*)kn_s;   // 8192 of 9216 floats used, [m][c] layout
    if (half == 1) {
        #pragma unroll
        for (int m = 0; m < CQK; ++m) xch[m*NC + px] = sacc[m];   // conflict-free
        xsx[px] = xsacc;
    }
    __syncthreads();
    const size_t base = (size_t)blockIdx.x * PARTF;
    if (half == 0) {
        #pragma unroll
        for (int m = 0; m < CQK; ++m) sacc[m] += xch[m*NC + px];
        xsacc += xsx[px];
        #pragma unroll
        for (int m = 0; m < CQK; ++m) partial[base + m*NC + px] = sacc[m];
        partial[base + CQK*NC + px] = xsacc;
    }
    if (tid < CQK) {
        float ks = 0.f;
        #pragma unroll
        for (int g = 0; g < 16; ++g) ks += ks2[g*32 + tid];
        partial[base + CQK*NC + NC + tid] = ks;
    }
}
__global__ __launch_bounds__(512) void pass1_kernel(
    const void* __restrict__ x, const float* __restrict__ wkqT,
    const float* __restrict__ bkq, float4* __restrict__ qn4,
    float* __restrict__ partial, const int* __restrict__ flag) {
    __shared__ __align__(16) float kn_s[TN][36];   // 36,864 B (reused as xch)
    __shared__ float ks2[16*32];                   //  2,048 B
    __shared__ float xsx[NC];                      //  1,024 B
    if (flag[0]) pass1_body<1>(x, wkqT, bkq, qn4, partial, kn_s, ks2, xsx);
    else         pass1_body<0>(x, wkqT, bkq, qn4, partial, kn_s, ks2, xsx);
}

// ---- pass 1.5: reduce partials; matrix^T [b][c][32], value_sum, k_sum ---------
template<int DT> __device__ __forceinline__ float dot256(const void* Wv, int row,
                                                         const float* sh) {
    float r = 0.f;
    for (int c0 = 0; c0 < NC; c0 += 8) {
        float xv[8]; ld8<DT>(Wv, (size_t)row * NC + c0, xv);
        #pragma unroll
        for (int i = 0; i < 8; ++i) r += xv[i] * sh[c0+i];
    }
    return r;
}
template<int DT> __device__ __forceinline__ void pass15_body(
    const float* __restrict__ partial, const void* __restrict__ Wv,
    const void* __restrict__ bv, float* __restrict__ matT,
    float* __restrict__ vsum, float* __restrict__ ksum, float* sh) {
    int tid = threadIdx.x;
    int b = blockIdx.x / 33, m = blockIdx.x % 33;
    const float* pb_ = partial + (size_t)b * PB1 * PARTF;

    if (m < CQK) {
        float acc = 0.f;
        #pragma unroll 4
        for (int p = 0; p < PB1; ++p) acc += pb_[(size_t)p*PARTF + m*NC + tid];
        sh[tid] = acc;
        float ks = 0.f;
        #pragma unroll 4
        for (int p = 0; p < PB1; ++p) ks += pb_[(size_t)p*PARTF + CQK*NC + NC + m];
        __syncthreads();
        float r = dot256<DT>(Wv, tid, sh);
        matT[((size_t)b*NC + tid)*CQK + m] = r + ldx<DT>(bv, tid) * ks;
        if (tid == 0) ksum[b*CQK + m] = ks + EPSV;
    } else {
        float acc = 0.f;
        #pragma unroll 4
        for (int p = 0; p < PB1; ++p) acc += pb_[(size_t)p*PARTF + CQK*NC + tid];
        sh[tid] = acc;
        __syncthreads();
        float r = dot256<DT>(Wv, tid, sh);
        vsum[b*NC + tid] = r + (float)NPIX * ldx<DT>(bv, tid);
    }
}
__global__ __launch_bounds__(256) void pass15_kernel(
    const float* __restrict__ partial, const void* __restrict__ Wv,
    const void* __restrict__ bv, float* __restrict__ matT,
    float* __restrict__ vsum, float* __restrict__ ksum,
    const int* __restrict__ flag) {
    __shared__ float sh[NC];
    if (flag[0]) pass15_body<1>(partial, Wv, bv, matT, vsum, ksum, sh);
    else         pass15_body<0>(partial, Wv, bv, matT, vsum, ksum, sh);
}

// ---- pass 2: epilogue. 1 px/thread, ci-step 16 (16 loads in flight). ----------
// grid = NB * 64 * 4 : (b, 256-pixel tile, 64-channel chunk)
template<int DT> __device__ __forceinline__ void pass2_body(
    const void* __restrict__ x, const float4* __restrict__ qn4,
    const float* __restrict__ ksum, const float* __restrict__ matT,
    const float* __restrict__ vsum, const void* __restrict__ gamma,
    float* __restrict__ out) {
    int tid = threadIdx.x;
    int bx = blockIdx.x;
    int cs = bx & 3, tile = (bx >> 2) & 63, b = bx >> 8;
    int p = tile * TN + tid;

    float q[CQK];
    const float4* qp = qn4 + (size_t)b * 8 * NPIX + p;
    #pragma unroll
    for (int m4 = 0; m4 < 8; ++m4) {
        float4 a = qp[(size_t)m4 * NPIX];
        q[m4*4+0]=a.x; q[m4*4+1]=a.y; q[m4*4+2]=a.z; q[m4*4+3]=a.w;
    }
    const float* ksb = ksum + b*CQK;   // uniform
    float dot = 0.f;
    #pragma unroll
    for (int m = 0; m < CQK; ++m) dot += q[m] * ksb[m];
    float gt = ldx<DT>(gamma, 0) / ((float)NPIX + dot);

    int c0 = cs * 64;
    const float* mb = matT + ((size_t)b*NC + c0)*CQK;  // uniform rows
    const float* vb = vsum + (size_t)b*NC + c0;
    size_t xbase = (size_t)b*NC*NPIX + (size_t)c0*NPIX + p;

    for (int ci = 0; ci < 64; ci += 16) {
        float xv[16];
        #pragma unroll
        for (int u = 0; u < 16; ++u)
            xv[u] = ldx<DT>(x, xbase + (size_t)(ci+u)*NPIX);
        #pragma unroll
        for (int u = 0; u < 16; ++u) {
            float r = vb[ci+u];
            const float4* mr = (const float4*)(mb + (ci+u)*CQK);  // uniform
            #pragma unroll
            for (int m4 = 0; m4 < 8; ++m4) {
                float4 a = mr[m4];
                r += q[m4*4+0]*a.x + q[m4*4+1]*a.y + q[m4*4+2]*a.z + q[m4*4+3]*a.w;
            }
            out[xbase + (size_t)(ci+u)*NPIX] = xv[u] + gt*r;
        }
    }
}
__global__ __launch_bounds__(256) void pass2_kernel(
    const void* __restrict__ x, const float4* __restrict__ qn4,
    const float* __restrict__ ksum, const float* __restrict__ matT,
    const float* __restrict__ vsum, const void* __restrict__ gamma,
    float* __restrict__ out, const int* __restrict__ flag) {
    if (flag[0]) pass2_body<1>(x, qn4, ksum, matT, vsum, gamma, out);
    else         pass2_body<0>(x, qn4, ksum, matT, vsum, gamma, out);
}

// ---- host ----------------------------------------------------------------------
extern "C" void kernel_launch(void* const* d_in, const int* in_sizes, int n_in,
                              void* d_out, int out_size, void* d_ws, size_t ws_size,
                              hipStream_t stream)
{
    const void* x  = d_in[0];
    const void* Wq = d_in[1];
    const void* bq = d_in[2];
    const void* Wk = d_in[3];
    const void* bk = d_in[4];
    const void* Wv = d_in[5];
    const void* bv = d_in[6];
    const void* gm = d_in[7];
    float* out = (float*)d_out;

    float* ws = (float*)d_ws;
    int*   flag = (int*)ws;             // 16 floats reserved
    float* wkqT = ws + 16;              // 16384
    float* bkq  = wkqT + 64*NC;         // 64
    float* matT = bkq + 64;             // NB*NC*CQK = 65536
    float* vsum = matT + NB*NC*CQK;     // 2048
    float* ksum = vsum + NB*NC;         // 256
    float* qn4f = ksum + NB*CQK;        // NB*8*NPIX*4 = 4194304 (16B-aligned)
    float* partial_ws = qn4f + (size_t)NB*8*NPIX*4;

    // Partial S scratch: NB*PB1*PARTF floats = 17.4 MB; total ws use 34.5 MB ==
    // the R0-proven-fit layout. d_out fallback kept only as a guard.
    size_t fixedf = (size_t)(partial_ws - ws);
    size_t needb  = (fixedf + (size_t)NB*PB1*PARTF) * sizeof(float);
    float* partial = (needb <= ws_size) ? partial_ws : (float*)d_out;

    hipLaunchKernelGGL(detprep_kernel, dim3(1), dim3(256), 0, stream,
                       (const bfraw*)x, Wq, bq, Wk, bk, flag, wkqT, bkq);
    hipLaunchKernelGGL(pass1_kernel, dim3(NB*PB1), dim3(512), 0, stream,
                       x, wkqT, bkq, (float4*)qn4f, partial, flag);
    hipLaunchKernelGGL(pass15_kernel, dim3(NB*33), dim3(256), 0, stream,
                       partial, Wv, bv, matT, vsum, ksum, flag);
    hipLaunchKernelGGL(pass2_kernel, dim3(NB*64*4), dim3(256), 0, stream,
                       x, (const float4*)qn4f, ksum, matT, vsum, gm, out, flag);
}